// Round 4
// baseline (546.664 us; speedup 1.0000x reference)
//
#include <hip/hip_runtime.h>

// Problem constants (fixed by setup_inputs / GTLModuleV1)
#define BATCH 4
#define CHAN  144
#define NPTS  16384
#define KNN   16
#define GRP   9
#define DIM   16
#define ROWF  (GRP * 2 * DIM)    // 288 floats per interleaved row (1152 B)
#define PCHUNK 16                // partial chunks per (b,g)
#define CPTS  (NPTS / PCHUNK)    // 1024 points per block

#define TT 32

// (C,N) -> interleaved (N, g, {key16|val16}) layout.
// z < BATCH: q slice (sel=0), else v slice (sel=16).
// Each (g,m) key+value pair lands in ONE aligned 128B line.
__global__ __launch_bounds__(256) void transpose_qv_kernel(
    const float* __restrict__ q, const float* __restrict__ v,
    float* __restrict__ qvT) {
  __shared__ float tile[TT][TT + 1];
  const int z = blockIdx.z;
  const int b = z & (BATCH - 1);
  const int sel = (z < BATCH) ? 0 : DIM;
  const float* in = (sel ? v : q) + (size_t)b * CHAN * NPTS;
  float* out = qvT + (size_t)b * NPTS * ROWF;
  const int n0 = blockIdx.x * TT;
  const int c0 = blockIdx.y * TT;
  const int t = threadIdx.x;

  {  // load: 32 channels x 32 points, float4 along n (coalesced)
    const int cl = t >> 3, nq = (t & 7) * 4;
    const int c = c0 + cl;
    if (c < CHAN) {
      const float4 ld = *(const float4*)&in[(size_t)c * NPTS + n0 + nq];
      tile[cl][nq + 0] = ld.x; tile[cl][nq + 1] = ld.y;
      tile[cl][nq + 2] = ld.z; tile[cl][nq + 3] = ld.w;
    }
  }
  __syncthreads();
  {  // store: float4 along c; c..c+3 stays within one group's 16-dim slice
    const int nl = t >> 3, cq = (t & 7) * 4;
    const int c = c0 + cq;
    if (c < CHAN) {
      const int g = c >> 4, d = c & 15;
      float4 st;
      st.x = tile[cq + 0][nl]; st.y = tile[cq + 1][nl];
      st.z = tile[cq + 2][nl]; st.w = tile[cq + 3][nl];
      *(float4*)&out[(size_t)(n0 + nl) * ROWF + g * (2 * DIM) + sel + d] = st;
    }
  }
}

// Wave = 4 points x 16 dims; 16 waves/block; block privatizes one (b,g)
// cent slice in 64KB LDS. Two passes per point (keys, then values) keep
// live registers ~ s[16] so 2 blocks (32 waves) fit per CU.
__global__ __launch_bounds__(1024, 8) void gtl_kernel(
    const float* __restrict__ qvT,  // (B, N, ROWF) interleaved
    const int*   __restrict__ idx,  // (B, N, K)
    float* __restrict__ feat,       // (B, C, N)
    float* __restrict__ part)       // (B, G, PCHUNK, NPTS)
{
  __shared__ float lcent[NPTS];     // 64 KB private cent[b,g,:]
  const int tid = threadIdx.x;

  float4* l4 = (float4*)lcent;
  #pragma unroll
  for (int i = 0; i < NPTS / 4 / 1024; ++i)
    l4[i * 1024 + tid] = make_float4(0.f, 0.f, 0.f, 0.f);
  __syncthreads();

  const int lane = tid & 63;
  const int wv   = tid >> 6;        // 16 waves / block
  const int slot = lane >> 4;       // point within wave [0,4)
  const int d    = lane & 15;       // dim within group [0,16)
  const int g = blockIdx.y;
  const int b = blockIdx.z;
  const int pbase = blockIdx.x * CPTS;

  // lane-d element of group-g key slice of row m is at base + m*ROWF;
  // matching value element at +DIM.
  const float* base = qvT + (size_t)b * NPTS * ROWF + g * (2 * DIM) + d;
  const int*   idxb = idx + (size_t)b * NPTS * KNN;

  for (int it = 0; it < CPTS / 64; ++it) {
    const int n = pbase + it * 64 + wv * 4 + slot;

    // lane d holds neighbor id k=d of its slot's point (coalesced 256B/wave)
    const int idxv = idxb[(size_t)n * KNN + d];
    const float qv = base[(size_t)n * ROWF];

    // ---- pass 1: gather keys, consume immediately into scores ----
    float s[KNN];
    #pragma unroll
    for (int k = 0; k < KNN; ++k) {
      const int mk = __shfl(idxv, slot * 16 + k);
      float p = base[(size_t)mk * ROWF] * qv;
      p += __shfl_xor(p, 1);
      p += __shfl_xor(p, 2);
      p += __shfl_xor(p, 4);
      p += __shfl_xor(p, 8);
      s[k] = p;
    }

    // ---- softmax over K=16 (redundant across lanes) ----
    float mx = s[0];
    #pragma unroll
    for (int k = 1; k < KNN; ++k) mx = fmaxf(mx, s[k]);
    float sum = 0.f;
    #pragma unroll
    for (int k = 0; k < KNN; ++k) { s[k] = __expf(s[k] - mx); sum += s[k]; }
    const float inv = 1.f / sum;

    // centrality: lane d scatters weight k=d of its slot's point
    float wsel = 0.f;
    #pragma unroll
    for (int k = 0; k < KNN; ++k) wsel = (d == k) ? s[k] : wsel;
    atomicAdd(&lcent[idxv], wsel * inv);

    // ---- pass 2: gather values (same 128B lines, L1/L2 warm), accumulate --
    float acc = 0.f;
    #pragma unroll
    for (int k = 0; k < KNN; ++k) {
      const int mk = __shfl(idxv, slot * 16 + k);
      acc += (s[k] * inv) * base[(size_t)mk * ROWF + DIM];
    }

    // feat write: (B,C,N), d stride NPTS, slot stride 1
    feat[((size_t)b * CHAN + g * DIM + d) * NPTS + n] = acc;
  }

  __syncthreads();
  // flush private slice to partials (non-atomic, coalesced float4)
  float4* p4 = (float4*)(part +
      (((size_t)(b * GRP + g)) * PCHUNK + blockIdx.x) * NPTS);
  #pragma unroll
  for (int i = 0; i < NPTS / 4 / 1024; ++i)
    p4[i * 1024 + tid] = l4[i * 1024 + tid];
}

// cent[b,g,m] = sum_p part[b,g,p,m]; thread per float4 of cent.
__global__ __launch_bounds__(256) void reduce_cent_kernel(
    const float* __restrict__ part, float* __restrict__ cent) {
  const int t = blockIdx.x * 256 + threadIdx.x;  // over 36 * 4096
  const int bg = t >> 12;
  const int m4 = (t & 4095) << 2;
  const float4* p = (const float4*)(part + ((size_t)bg * PCHUNK) * NPTS + m4);
  float4 s = make_float4(0.f, 0.f, 0.f, 0.f);
  #pragma unroll
  for (int i = 0; i < PCHUNK; ++i) {
    float4 x = p[(size_t)i * (NPTS / 4)];
    s.x += x.x; s.y += x.y; s.z += x.z; s.w += x.w;
  }
  *(float4*)(cent + (size_t)bg * NPTS + m4) = s;
}

extern "C" void kernel_launch(void* const* d_in, const int* in_sizes, int n_in,
                              void* d_out, int out_size, void* d_ws, size_t ws_size,
                              hipStream_t stream) {
  const float* q   = (const float*)d_in[0];   // queryandkey (B,C,N)
  const float* v   = (const float*)d_in[1];   // value (B,C,N)
  const int*   idx = (const int*)d_in[2];     // idx_knn (B,N,K)

  float* feat = (float*)d_out;                       // (B,C,N)
  float* cent = feat + (size_t)BATCH * CHAN * NPTS;  // (B,G,N)

  float* qvT  = (float*)d_ws;                            // (B,N,ROWF)
  float* part = qvT + (size_t)BATCH * NPTS * ROWF;       // (B,G,PCHUNK,NPTS)

  // 1) transpose q,v into interleaved key|value row layout
  dim3 tg(NPTS / TT, (CHAN + TT - 1) / TT, BATCH * 2);
  transpose_qv_kernel<<<tg, 256, 0, stream>>>(q, v, qvT);

  // 2) main fused kernel: 576 blocks x 1024 threads, 64KB LDS each
  dim3 gb(PCHUNK, GRP, BATCH);
  gtl_kernel<<<gb, 1024, 0, stream>>>(qvT, idx, feat, part);

  // 3) reduce partials -> cent (writes every element; no memset needed)
  reduce_cent_kernel<<<(GRP * BATCH * NPTS / 4) / 256, 256, 0, stream>>>(part, cent);
}

// Round 5
// 356.952 us; speedup vs baseline: 1.5315x; 1.5315x over previous
//
#include <hip/hip_runtime.h>
#include <hip/hip_fp16.h>

// Problem constants (fixed by setup_inputs / GTLModuleV1)
#define BATCH 4
#define CHAN  144
#define NPTS  16384
#define KNN   16
#define GRP   9
#define DIM   16
#define ROWU  (GRP * DIM)        // 144 uint32 per point = 288 fp16 = 576 B
#define PCHUNK 16                // partial chunks per (b,g)
#define CPTS  (NPTS / PCHUNK)    // 1024 points per block
#define NPAIR (BATCH * GRP)      // 36

#define TT 32

// (C,N) fp32 q,v -> (N, c) packed fp16 pairs: out[n*144 + c] = (h(q), h(v)).
// Each (g,m) slice = 16 uints = 64 B, 64B-aligned (576 = 9*64).
__global__ __launch_bounds__(256) void pack_qv_kernel(
    const float* __restrict__ q, const float* __restrict__ v,
    unsigned int* __restrict__ qvT) {
  __shared__ float tq[TT][TT + 1];
  __shared__ float tv[TT][TT + 1];
  const int b = blockIdx.z;
  const float* qb = q + (size_t)b * CHAN * NPTS;
  const float* vb = v + (size_t)b * CHAN * NPTS;
  unsigned int* out = qvT + (size_t)b * NPTS * ROWU;
  const int n0 = blockIdx.x * TT;
  const int c0 = blockIdx.y * TT;
  const int t = threadIdx.x;

  {  // load both tiles: float4 along n (coalesced)
    const int cl = t >> 3, nq = (t & 7) * 4;
    const int c = c0 + cl;
    if (c < CHAN) {
      const float4 a = *(const float4*)&qb[(size_t)c * NPTS + n0 + nq];
      tq[cl][nq + 0] = a.x; tq[cl][nq + 1] = a.y;
      tq[cl][nq + 2] = a.z; tq[cl][nq + 3] = a.w;
      const float4 w = *(const float4*)&vb[(size_t)c * NPTS + n0 + nq];
      tv[cl][nq + 0] = w.x; tv[cl][nq + 1] = w.y;
      tv[cl][nq + 2] = w.z; tv[cl][nq + 3] = w.w;
    }
  }
  __syncthreads();
  {  // store packed pairs: uint4 along c (coalesced)
    const int nl = t >> 3, cq = (t & 7) * 4;
    const int c = c0 + cq;
    if (c < CHAN) {
      unsigned int u[4];
      #pragma unroll
      for (int j = 0; j < 4; ++j) {
        __half2 h = __halves2half2(__float2half_rn(tq[cq + j][nl]),
                                   __float2half_rn(tv[cq + j][nl]));
        u[j] = *(unsigned int*)&h;
      }
      *(uint4*)&out[(size_t)(n0 + nl) * ROWU + c] =
          make_uint4(u[0], u[1], u[2], u[3]);
    }
  }
}

// Wave = 4 points x 16 dims; 16 waves/block; block privatizes one (b,g)
// cent slice in 64KB LDS. One packed fp16 gather fetches key+value.
// 1D grid swizzled so all 16 chunks of a (b,g) pair share one XCD (i%8),
// balanced 72 blocks/XCD.
__global__ __launch_bounds__(1024, 8) void gtl_kernel(
    const unsigned int* __restrict__ qvT,  // (B, N, ROWU) packed
    const int*   __restrict__ idx,         // (B, N, K)
    float* __restrict__ feat,              // (B, C, N)
    float* __restrict__ part)              // (B, G, PCHUNK, NPTS)
{
  __shared__ float lcent[NPTS];     // 64 KB private cent[b,g,:]
  const int tid = threadIdx.x;

  float4* l4 = (float4*)lcent;
  #pragma unroll
  for (int i = 0; i < NPTS / 4 / 1024; ++i)
    l4[i * 1024 + tid] = make_float4(0.f, 0.f, 0.f, 0.f);
  __syncthreads();

  // ---- XCD-partitioned decode: i%8 is constant per (b,g) pair ----
  const int i = blockIdx.x;        // 0..575
  const int x = i & 7, sblk = i >> 3;   // sblk in 0..71
  int pair, chunk;
  if (sblk < 64) { pair = x + 8 * (sblk >> 4); chunk = sblk & 15; }
  else           { pair = 32 + (x >> 1); chunk = (sblk - 64) + 8 * (x & 1); }
  const int b = pair / GRP;
  const int g = pair - b * GRP;

  const int lane = tid & 63;
  const int wv   = tid >> 6;        // 16 waves / block
  const int slot = lane >> 4;       // point within wave [0,4)
  const int d    = lane & 15;       // dim within group [0,16)
  const int pbase = chunk * CPTS;

  const unsigned int* base = qvT + (size_t)b * NPTS * ROWU + g * DIM + d;
  const int* idxb = idx + (size_t)b * NPTS * KNN;

  for (int it = 0; it < CPTS / 64; ++it) {
    const int n = pbase + it * 64 + wv * 4 + slot;

    // lane d holds neighbor id k=d of its slot's point (coalesced 256B/wave)
    const int idxv = idxb[(size_t)n * KNN + d];
    const unsigned int qu = base[(size_t)n * ROWU];
    const float qv = __half2float(((const __half2*)&qu)->x);

    // ---- burst: 16 packed gathers fetch key+value together (64B/line) ----
    unsigned int kv[KNN];
    #pragma unroll
    for (int k = 0; k < KNN; ++k) {
      const int mk = __shfl(idxv, slot * 16 + k);
      kv[k] = base[(size_t)mk * ROWU];
    }

    // ---- scores: butterfly reduce over the 16-lane dim group ----
    float s[KNN];
    #pragma unroll
    for (int k = 0; k < KNN; ++k) {
      float p = __half2float(((const __half2*)&kv[k])->x) * qv;
      p += __shfl_xor(p, 1);
      p += __shfl_xor(p, 2);
      p += __shfl_xor(p, 4);
      p += __shfl_xor(p, 8);
      s[k] = p;
    }

    // ---- softmax over K=16 (redundant across lanes) ----
    float mx = s[0];
    #pragma unroll
    for (int k = 1; k < KNN; ++k) mx = fmaxf(mx, s[k]);
    float sum = 0.f;
    #pragma unroll
    for (int k = 0; k < KNN; ++k) { s[k] = __expf(s[k] - mx); sum += s[k]; }
    const float inv = 1.f / sum;

    // centrality: lane d scatters weight k=d of its slot's point
    float wsel = 0.f;
    #pragma unroll
    for (int k = 0; k < KNN; ++k) wsel = (d == k) ? s[k] : wsel;
    atomicAdd(&lcent[idxv], wsel * inv);

    // ---- weighted value aggregation from the packed registers ----
    float acc = 0.f;
    #pragma unroll
    for (int k = 0; k < KNN; ++k)
      acc += (s[k] * inv) * __half2float(((const __half2*)&kv[k])->y);

    // feat write: (B,C,N), d stride NPTS, slot stride 1
    feat[((size_t)b * CHAN + g * DIM + d) * NPTS + n] = acc;
  }

  __syncthreads();
  // flush private slice to partials (non-atomic, coalesced float4)
  float4* p4 = (float4*)(part +
      (((size_t)(b * GRP + g)) * PCHUNK + chunk) * NPTS);
  #pragma unroll
  for (int i2 = 0; i2 < NPTS / 4 / 1024; ++i2)
    p4[i2 * 1024 + tid] = l4[i2 * 1024 + tid];
}

// cent[b,g,m] = sum_p part[b,g,p,m]; thread per float4 of cent.
__global__ __launch_bounds__(256) void reduce_cent_kernel(
    const float* __restrict__ part, float* __restrict__ cent) {
  const int t = blockIdx.x * 256 + threadIdx.x;  // over 36 * 4096
  const int bg = t >> 12;
  const int m4 = (t & 4095) << 2;
  const float4* p = (const float4*)(part + ((size_t)bg * PCHUNK) * NPTS + m4);
  float4 s = make_float4(0.f, 0.f, 0.f, 0.f);
  #pragma unroll
  for (int i = 0; i < PCHUNK; ++i) {
    float4 x = p[(size_t)i * (NPTS / 4)];
    s.x += x.x; s.y += x.y; s.z += x.z; s.w += x.w;
  }
  *(float4*)(cent + (size_t)bg * NPTS + m4) = s;
}

extern "C" void kernel_launch(void* const* d_in, const int* in_sizes, int n_in,
                              void* d_out, int out_size, void* d_ws, size_t ws_size,
                              hipStream_t stream) {
  const float* q   = (const float*)d_in[0];   // queryandkey (B,C,N)
  const float* v   = (const float*)d_in[1];   // value (B,C,N)
  const int*   idx = (const int*)d_in[2];     // idx_knn (B,N,K)

  float* feat = (float*)d_out;                       // (B,C,N)
  float* cent = feat + (size_t)BATCH * CHAN * NPTS;  // (B,G,N)

  unsigned int* qvT = (unsigned int*)d_ws;               // (B,N,ROWU) packed
  float* part = (float*)(qvT + (size_t)BATCH * NPTS * ROWU);  // (B,G,16,N)

  // 1) pack q,v into interleaved fp16 (key,val) rows
  dim3 tg(NPTS / TT, (CHAN + TT - 1) / TT, BATCH);
  pack_qv_kernel<<<tg, 256, 0, stream>>>(q, v, qvT);

  // 2) main fused kernel: 576 blocks x 1024 threads, 64KB LDS, XCD swizzle
  gtl_kernel<<<NPAIR * PCHUNK, 1024, 0, stream>>>(qvT, idx, feat, part);

  // 3) reduce partials -> cent (writes every element; no memset needed)
  reduce_cent_kernel<<<(GRP * BATCH * NPTS / 4) / 256, 256, 0, stream>>>(part, cent);
}

// Round 6
// 309.678 us; speedup vs baseline: 1.7653x; 1.1527x over previous
//
#include <hip/hip_runtime.h>
#include <hip/hip_fp16.h>

// Problem constants (fixed by setup_inputs / GTLModuleV1)
#define BATCH 4
#define CHAN  144
#define NPTS  16384
#define KNN   16
#define GRP   9
#define DIM   16
#define ROWU  (GRP * DIM)        // 144 uint32 per point = 288 fp16 = 576 B
#define PCHUNK 14                // chunks per (b,g) pair -> 36*14 = 504 blocks
#define NPAIR (BATCH * GRP)      // 36
#define NGRP64 (NPTS / 64)       // 256 groups of 64 points per pair

#define TT 32

// (C,N) fp32 q,v -> (N, c) packed fp16 pairs: out[n*144 + c] = (h(q), h(v)).
// Each (g,m) slice = 16 uints = 64 B, 64B-aligned (576 = 9*64).
__global__ __launch_bounds__(256) void pack_qv_kernel(
    const float* __restrict__ q, const float* __restrict__ v,
    unsigned int* __restrict__ qvT) {
  __shared__ float tq[TT][TT + 1];
  __shared__ float tv[TT][TT + 1];
  const int b = blockIdx.z;
  const float* qb = q + (size_t)b * CHAN * NPTS;
  const float* vb = v + (size_t)b * CHAN * NPTS;
  unsigned int* out = qvT + (size_t)b * NPTS * ROWU;
  const int n0 = blockIdx.x * TT;
  const int c0 = blockIdx.y * TT;
  const int t = threadIdx.x;

  {  // load both tiles: float4 along n (coalesced)
    const int cl = t >> 3, nq = (t & 7) * 4;
    const int c = c0 + cl;
    if (c < CHAN) {
      const float4 a = *(const float4*)&qb[(size_t)c * NPTS + n0 + nq];
      tq[cl][nq + 0] = a.x; tq[cl][nq + 1] = a.y;
      tq[cl][nq + 2] = a.z; tq[cl][nq + 3] = a.w;
      const float4 w = *(const float4*)&vb[(size_t)c * NPTS + n0 + nq];
      tv[cl][nq + 0] = w.x; tv[cl][nq + 1] = w.y;
      tv[cl][nq + 2] = w.z; tv[cl][nq + 3] = w.w;
    }
  }
  __syncthreads();
  {  // store packed pairs: uint4 along c (coalesced)
    const int nl = t >> 3, cq = (t & 7) * 4;
    const int c = c0 + cq;
    if (c < CHAN) {
      unsigned int u[4];
      #pragma unroll
      for (int j = 0; j < 4; ++j) {
        __half2 h = __halves2half2(__float2half_rn(tq[cq + j][nl]),
                                   __float2half_rn(tv[cq + j][nl]));
        u[j] = *(unsigned int*)&h;
      }
      *(uint4*)&out[(size_t)(n0 + nl) * ROWU + c] =
          make_uint4(u[0], u[1], u[2], u[3]);
    }
  }
}

// Wave = 4 points x 16 dims; 16 waves/block; block privatizes one (b,g)
// cent slice in 64KB LDS. One packed fp16 gather fetches key+value.
// 504 blocks = single residency round (2 blocks/CU, 63/64 slots per XCD);
// all chunks of a (b,g) pair share i%8 (same XCD) for L2 gather locality.
__global__ __launch_bounds__(1024, 8) void gtl_kernel(
    const unsigned int* __restrict__ qvT,  // (B, N, ROWU) packed
    const int*   __restrict__ idx,         // (B, N, K)
    float* __restrict__ feat,              // (B, C, N)
    float* __restrict__ part)              // (NPAIR, PCHUNK, NPTS)
{
  __shared__ float lcent[NPTS];     // 64 KB private cent[b,g,:]
  const int tid = threadIdx.x;

  float4* l4 = (float4*)lcent;
  #pragma unroll
  for (int i = 0; i < NPTS / 4 / 1024; ++i)
    l4[i * 1024 + tid] = make_float4(0.f, 0.f, 0.f, 0.f);
  __syncthreads();

  // ---- XCD-partitioned decode: i%8 constant per (b,g) pair ----
  const int i = blockIdx.x;           // 0..503
  const int x = i & 7, sblk = i >> 3; // sblk in 0..62
  int pair, chunk;
  if (sblk < 56) { pair = x + 8 * (sblk / PCHUNK); chunk = sblk % PCHUNK; }
  else           { pair = 32 + (x >> 1); chunk = (sblk - 56) + 7 * (x & 1); }
  const int b = pair / GRP;
  const int g = pair - b * GRP;

  // chunk -> contiguous range of 64-point groups (first 4 chunks get 19)
  const int ngroups = 18 + (chunk < 4 ? 1 : 0);
  const int gstart  = 18 * chunk + (chunk < 4 ? chunk : 4);

  const int lane = tid & 63;
  const int wv   = tid >> 6;        // 16 waves / block
  const int slot = lane >> 4;       // point within wave [0,4)
  const int d    = lane & 15;       // dim within group [0,16)

  const unsigned int* base = qvT + (size_t)b * NPTS * ROWU + g * DIM + d;
  const int* idxb = idx + (size_t)b * NPTS * KNN;

  for (int it = 0; it < ngroups; ++it) {
    const int n = (gstart + it) * 64 + wv * 4 + slot;

    // lane d holds neighbor id k=d of its slot's point (coalesced 256B/wave)
    const int idxv = idxb[(size_t)n * KNN + d];
    const unsigned int qu = base[(size_t)n * ROWU];
    const float qv = __half2float(((const __half2*)&qu)->x);

    // ---- burst: 16 packed gathers fetch key+value together (64B/slice) ----
    unsigned int kv[KNN];
    #pragma unroll
    for (int k = 0; k < KNN; ++k) {
      const int mk = __shfl(idxv, slot * 16 + k);
      kv[k] = base[(size_t)mk * ROWU];
    }

    // ---- scores: butterfly reduce over the 16-lane dim group ----
    float s[KNN];
    #pragma unroll
    for (int k = 0; k < KNN; ++k) {
      float p = __half2float(((const __half2*)&kv[k])->x) * qv;
      p += __shfl_xor(p, 1);
      p += __shfl_xor(p, 2);
      p += __shfl_xor(p, 4);
      p += __shfl_xor(p, 8);
      s[k] = p;
    }

    // ---- softmax over K=16 (redundant across lanes) ----
    float mx = s[0];
    #pragma unroll
    for (int k = 1; k < KNN; ++k) mx = fmaxf(mx, s[k]);
    float sum = 0.f;
    #pragma unroll
    for (int k = 0; k < KNN; ++k) { s[k] = __expf(s[k] - mx); sum += s[k]; }
    const float inv = 1.f / sum;

    // centrality: lane d scatters weight k=d of its slot's point
    float wsel = 0.f;
    #pragma unroll
    for (int k = 0; k < KNN; ++k) wsel = (d == k) ? s[k] : wsel;
    atomicAdd(&lcent[idxv], wsel * inv);

    // ---- weighted value aggregation from the packed registers ----
    float acc = 0.f;
    #pragma unroll
    for (int k = 0; k < KNN; ++k)
      acc += (s[k] * inv) * __half2float(((const __half2*)&kv[k])->y);

    // feat write: (B,C,N), d stride NPTS, slot stride 1
    feat[((size_t)b * CHAN + g * DIM + d) * NPTS + n] = acc;
  }

  __syncthreads();
  // flush private slice to partials (non-atomic, coalesced float4)
  float4* p4 = (float4*)(part + ((size_t)pair * PCHUNK + chunk) * NPTS);
  #pragma unroll
  for (int i2 = 0; i2 < NPTS / 4 / 1024; ++i2)
    p4[i2 * 1024 + tid] = l4[i2 * 1024 + tid];
}

// cent[bg,m] = sum_p part[bg,p,m]; thread per float4 of cent.
__global__ __launch_bounds__(256) void reduce_cent_kernel(
    const float* __restrict__ part, float* __restrict__ cent) {
  const int t = blockIdx.x * 256 + threadIdx.x;  // over 36 * 4096
  const int bg = t >> 12;
  const int m4 = (t & 4095) << 2;
  const float4* p = (const float4*)(part + ((size_t)bg * PCHUNK) * NPTS + m4);
  float4 s = make_float4(0.f, 0.f, 0.f, 0.f);
  #pragma unroll
  for (int i = 0; i < PCHUNK; ++i) {
    float4 x = p[(size_t)i * (NPTS / 4)];
    s.x += x.x; s.y += x.y; s.z += x.z; s.w += x.w;
  }
  *(float4*)(cent + (size_t)bg * NPTS + m4) = s;
}

extern "C" void kernel_launch(void* const* d_in, const int* in_sizes, int n_in,
                              void* d_out, int out_size, void* d_ws, size_t ws_size,
                              hipStream_t stream) {
  const float* q   = (const float*)d_in[0];   // queryandkey (B,C,N)
  const float* v   = (const float*)d_in[1];   // value (B,C,N)
  const int*   idx = (const int*)d_in[2];     // idx_knn (B,N,K)

  float* feat = (float*)d_out;                       // (B,C,N)
  float* cent = feat + (size_t)BATCH * CHAN * NPTS;  // (B,G,N)

  unsigned int* qvT = (unsigned int*)d_ws;               // (B,N,ROWU) packed
  float* part = (float*)(qvT + (size_t)BATCH * NPTS * ROWU);  // (36,14,N)

  // 1) pack q,v into interleaved fp16 (key,val) rows
  dim3 tg(NPTS / TT, (CHAN + TT - 1) / TT, BATCH);
  pack_qv_kernel<<<tg, 256, 0, stream>>>(q, v, qvT);

  // 2) main fused kernel: 504 blocks x 1024 threads, 64KB LDS, XCD swizzle
  gtl_kernel<<<NPAIR * PCHUNK, 1024, 0, stream>>>(qvT, idx, feat, part);

  // 3) reduce partials -> cent (writes every element; no memset needed)
  reduce_cent_kernel<<<(NPAIR * NPTS / 4) / 256, 256, 0, stream>>>(part, cent);
}

// Round 7
// 250.917 us; speedup vs baseline: 2.1787x; 1.2342x over previous
//
#include <hip/hip_runtime.h>
#include <hip/hip_fp16.h>

// Problem constants (fixed by setup_inputs / GTLModuleV1)
#define BATCH 4
#define CHAN  144
#define NPTS  16384
#define KNN   16
#define GRP   9
#define DIM   16
#define ROWU  (GRP * DIM)        // 144 uint32 per point = 576 B row
#define PCHUNK 14                // chunks per (b,g) pair -> 36*14 = 504 blocks
#define NPAIR (BATCH * GRP)      // 36

#define TT 32

typedef __attribute__((ext_vector_type(2))) _Float16 h2v;
__device__ __forceinline__ h2v as_h2(unsigned int u) {
  union { unsigned int u; h2v h; } c; c.u = u; return c.h;
}

// (C,N) fp32 q,v -> (N, 144 uints): per group g, uint 2i = h2(k_{2i},k_{2i+1}),
// uint 2i+1 = h2(v_{2i},v_{2i+1}). Each (g,m) slice = 64 B; lane-pair slice
// (2 dims of key+val) = one 8 B uint2.
__global__ __launch_bounds__(256) void pack_qv_kernel(
    const float* __restrict__ q, const float* __restrict__ v,
    unsigned int* __restrict__ qvT) {
  __shared__ float tq[TT][TT + 1];
  __shared__ float tv[TT][TT + 1];
  const int b = blockIdx.z;
  const float* qb = q + (size_t)b * CHAN * NPTS;
  const float* vb = v + (size_t)b * CHAN * NPTS;
  unsigned int* out = qvT + (size_t)b * NPTS * ROWU;
  const int n0 = blockIdx.x * TT;
  const int c0 = blockIdx.y * TT;
  const int t = threadIdx.x;

  {  // load both tiles: float4 along n (coalesced)
    const int cl = t >> 3, nq = (t & 7) * 4;
    const int c = c0 + cl;
    if (c < CHAN) {
      const float4 a = *(const float4*)&qb[(size_t)c * NPTS + n0 + nq];
      tq[cl][nq + 0] = a.x; tq[cl][nq + 1] = a.y;
      tq[cl][nq + 2] = a.z; tq[cl][nq + 3] = a.w;
      const float4 w = *(const float4*)&vb[(size_t)c * NPTS + n0 + nq];
      tv[cl][nq + 0] = w.x; tv[cl][nq + 1] = w.y;
      tv[cl][nq + 2] = w.z; tv[cl][nq + 3] = w.w;
    }
  }
  __syncthreads();
  {  // store packed dim-pairs: uint4 along c (coalesced)
    const int nl = t >> 3, cq = (t & 7) * 4;
    const int c = c0 + cq;   // multiple of 4
    if (c < CHAN) {
      const int g = c >> 4, r = c & 15;   // r in {0,4,8,12}
      __half2 k01 = __halves2half2(__float2half_rn(tq[cq + 0][nl]),
                                   __float2half_rn(tq[cq + 1][nl]));
      __half2 v01 = __halves2half2(__float2half_rn(tv[cq + 0][nl]),
                                   __float2half_rn(tv[cq + 1][nl]));
      __half2 k23 = __halves2half2(__float2half_rn(tq[cq + 2][nl]),
                                   __float2half_rn(tq[cq + 3][nl]));
      __half2 v23 = __halves2half2(__float2half_rn(tv[cq + 2][nl]),
                                   __float2half_rn(tv[cq + 3][nl]));
      *(uint4*)&out[(size_t)(n0 + nl) * ROWU + g * 16 + r] =
          make_uint4(*(unsigned int*)&k01, *(unsigned int*)&v01,
                     *(unsigned int*)&k23, *(unsigned int*)&v23);
    }
  }
}

// Wave = 8 points x 8 dim-pair lanes; 16 waves/block; block privatizes one
// (b,g) cent slice in 64KB LDS. One uint2 gather per (point, neighbor)
// fetches 2 key dims + 2 value dims; butterfly is 3 levels over 8 lanes.
// 504 blocks = single residency round; chunks of a pair share i%8 (XCD).
__global__ __launch_bounds__(1024, 8) void gtl_kernel(
    const unsigned int* __restrict__ qvT,  // (B, N, ROWU) packed
    const int*   __restrict__ idx,         // (B, N, K)
    float* __restrict__ feat,              // (B, C, N)
    float* __restrict__ part)              // (NPAIR, PCHUNK, NPTS)
{
  __shared__ float lcent[NPTS];     // 64 KB private cent[b,g,:]
  const int tid = threadIdx.x;

  float4* l4 = (float4*)lcent;
  #pragma unroll
  for (int i = 0; i < NPTS / 4 / 1024; ++i)
    l4[i * 1024 + tid] = make_float4(0.f, 0.f, 0.f, 0.f);
  __syncthreads();

  // ---- XCD-partitioned decode: i%8 constant per (b,g) pair ----
  const int i = blockIdx.x;           // 0..503
  const int x = i & 7, sblk = i >> 3; // sblk in 0..62
  int pair, chunk;
  if (sblk < 56) { pair = x + 8 * (sblk / PCHUNK); chunk = sblk % PCHUNK; }
  else           { pair = 32 + (x >> 1); chunk = (sblk - 56) + 7 * (x & 1); }
  const int b = pair / GRP;
  const int g = pair - b * GRP;

  // chunk -> contiguous range of 128-point groups (128 groups per pair)
  const int ngroups = 9 + (chunk < 2 ? 1 : 0);
  const int gstart  = 9 * chunk + (chunk < 2 ? chunk : 2);

  const int lane = tid & 63;
  const int wv   = tid >> 6;        // 16 waves / block
  const int slot = lane >> 3;       // point within wave [0,8)
  const int d2   = lane & 7;        // dim-pair within group [0,8)

  const unsigned int* base = qvT + (size_t)b * NPTS * ROWU + g * DIM + 2 * d2;
  const int* idxb = idx + (size_t)b * NPTS * KNN;

  for (int it = 0; it < ngroups; ++it) {
    const int n = (gstart + it) * 128 + wv * 8 + slot;

    // lane d2 holds neighbor ids 2d2, 2d2+1 of its point (512B/wave, coal.)
    const int2 idxv = *(const int2*)(idxb + (size_t)n * KNN + 2 * d2);
    const unsigned int qu = base[(size_t)n * ROWU];
    const h2v qk = as_h2(qu);

    // ---- burst: 16 uint2 gathers = 8 points x 16 neighbors ----
    uint2 kvp[KNN];
    #pragma unroll
    for (int k = 0; k < KNN; ++k) {
      const int mk = __shfl((k & 1) ? idxv.y : idxv.x, slot * 8 + (k >> 1));
      kvp[k] = *(const uint2*)(base + (size_t)mk * ROWU);
    }

    // ---- scores: fdot2 + 3-level butterfly over the 8-lane group ----
    float s[KNN];
    #pragma unroll
    for (int k = 0; k < KNN; ++k) {
#if __has_builtin(__builtin_amdgcn_fdot2)
      float p = __builtin_amdgcn_fdot2(as_h2(kvp[k].x), qk, 0.f, false);
#else
      const float2 kf = __half22float2(*(const __half2*)&kvp[k].x);
      const float2 qf = __half22float2(*(const __half2*)&qu);
      float p = kf.x * qf.x + kf.y * qf.y;
#endif
      p += __shfl_xor(p, 1);
      p += __shfl_xor(p, 2);
      p += __shfl_xor(p, 4);
      s[k] = p;
    }

    // ---- softmax over K=16 (redundant across the 8 lanes) ----
    float mx = s[0];
    #pragma unroll
    for (int k = 1; k < KNN; ++k) mx = fmaxf(mx, s[k]);
    float sum = 0.f;
    #pragma unroll
    for (int k = 0; k < KNN; ++k) { s[k] = __expf(s[k] - mx); sum += s[k]; }
    const float inv = 1.f / sum;

    // centrality: lane d2 scatters weights k=2d2 (idxv.x) and 2d2+1 (idxv.y)
    float w0 = 0.f, w1 = 0.f;
    #pragma unroll
    for (int k = 0; k < KNN; k += 2) w0 = (d2 == (k >> 1)) ? s[k] : w0;
    #pragma unroll
    for (int k = 1; k < KNN; k += 2) w1 = (d2 == (k >> 1)) ? s[k] : w1;
    atomicAdd(&lcent[idxv.x], w0 * inv);
    atomicAdd(&lcent[idxv.y], w1 * inv);

    // ---- weighted value aggregation (2 dims per lane) ----
    float ax = 0.f, ay = 0.f;
    #pragma unroll
    for (int k = 0; k < KNN; ++k) {
      const float wk = s[k] * inv;
      const float2 vf = __half22float2(*(const __half2*)&kvp[k].y);
      ax += wk * vf.x; ay += wk * vf.y;
    }

    // feat write: dims 2d2, 2d2+1 of point n; 32B segments per (d2, store)
    float* fb = feat + ((size_t)b * CHAN + g * DIM + 2 * d2) * NPTS + n;
    fb[0] = ax;
    fb[NPTS] = ay;
  }

  __syncthreads();
  // flush private slice to partials (non-atomic, coalesced float4)
  float4* p4 = (float4*)(part + ((size_t)pair * PCHUNK + chunk) * NPTS);
  #pragma unroll
  for (int i2 = 0; i2 < NPTS / 4 / 1024; ++i2)
    p4[i2 * 1024 + tid] = l4[i2 * 1024 + tid];
}

// cent[bg,m] = sum_p part[bg,p,m]; thread per float4 of cent.
__global__ __launch_bounds__(256) void reduce_cent_kernel(
    const float* __restrict__ part, float* __restrict__ cent) {
  const int t = blockIdx.x * 256 + threadIdx.x;  // over 36 * 4096
  const int bg = t >> 12;
  const int m4 = (t & 4095) << 2;
  const float4* p = (const float4*)(part + ((size_t)bg * PCHUNK) * NPTS + m4);
  float4 s = make_float4(0.f, 0.f, 0.f, 0.f);
  #pragma unroll
  for (int i = 0; i < PCHUNK; ++i) {
    float4 x = p[(size_t)i * (NPTS / 4)];
    s.x += x.x; s.y += x.y; s.z += x.z; s.w += x.w;
  }
  *(float4*)(cent + (size_t)bg * NPTS + m4) = s;
}

extern "C" void kernel_launch(void* const* d_in, const int* in_sizes, int n_in,
                              void* d_out, int out_size, void* d_ws, size_t ws_size,
                              hipStream_t stream) {
  const float* q   = (const float*)d_in[0];   // queryandkey (B,C,N)
  const float* v   = (const float*)d_in[1];   // value (B,C,N)
  const int*   idx = (const int*)d_in[2];     // idx_knn (B,N,K)

  float* feat = (float*)d_out;                       // (B,C,N)
  float* cent = feat + (size_t)BATCH * CHAN * NPTS;  // (B,G,N)

  unsigned int* qvT = (unsigned int*)d_ws;               // (B,N,ROWU) packed
  float* part = (float*)(qvT + (size_t)BATCH * NPTS * ROWU);  // (36,14,N)

  // 1) pack q,v into dim-pair interleaved fp16 rows
  dim3 tg(NPTS / TT, (CHAN + TT - 1) / TT, BATCH);
  pack_qv_kernel<<<tg, 256, 0, stream>>>(q, v, qvT);

  // 2) main fused kernel: 504 blocks x 1024 threads, 64KB LDS, XCD swizzle
  gtl_kernel<<<NPAIR * PCHUNK, 1024, 0, stream>>>(qvT, idx, feat, part);

  // 3) reduce partials -> cent (writes every element; no memset needed)
  reduce_cent_kernel<<<(NPAIR * NPTS / 4) / 256, 256, 0, stream>>>(part, cent);
}